// Round 2
// baseline (62.375 us; speedup 1.0000x reference)
//
#include <hip/hip_runtime.h>

#define OUTP 7
#define CCH  512
#define HF   50
#define WF   50
#define NROI 256
#define RSTR 34    // LDS row stride in floats: even (8B-aligned float2) and != 0 mod 32
#define RROWS 24

// One wave per (n, c). Wave w handles RoI n = w>>5, channels c0..c0+15 with
// c0 = (w&31)*16. Region (<=24 rows x 32 cols) staged to per-wave LDS with
// coalesced float2 loads (4 rows / wave-load), then 49 lanes compute their
// window max from LDS. All roi math amortized over 16 channels.
__global__ __launch_bounds__(256) void roipool_kernel(
    const float* __restrict__ x,
    const float* __restrict__ rois,
    float* __restrict__ out)
{
    __shared__ float lds[4][RROWS * RSTR];   // 4 waves * 3264 B = 13056 B

    const int tid  = threadIdx.x;
    const int wv   = tid >> 6;
    const int lane = tid & 63;
    float* R = lds[wv];

    const int w  = blockIdx.x * 4 + wv;      // global wave id, 0..8191
    const int n  = w >> 5;                   // RoI id 0..255
    const int c0 = (w & 31) << 4;            // first of 16 channels

    // per-lane constants
    const int ph = lane / 7;                 // valid for lane<49
    const int pw = lane - ph * 7;
    const int ly = lane >> 4;                // stage row within 4-row group
    const int lx = (lane & 15) << 1;         // stage col (floats), 0..30

    // roi (uniform per wave); scale 50/800 = 0.0625 exact, trunc == astype(int32)
    const float4 rv = *(const float4*)(rois + n * 4);
    const int rx = (int)(rv.x * 0.0625f);
    const int ry = (int)(rv.y * 0.0625f);
    const int sw = (int)(rv.z * 0.0625f) + 1;
    const int sh = (int)(rv.w * 0.0625f) + 1;
    const int x02 = rx & ~1;                 // 8B-aligned col start
    const int dx  = rx & 1;
    const int jmax = (sh + 3) >> 2;          // 4-row groups to stage (<=6)

    // per-lane output window, LDS-relative (valid for lane<49)
    const int ys = (ph * sh) / 7;
    const int ye = ((ph + 1) * sh + 6) / 7;
    const int xs = (pw * sw) / 7 + dx;
    const int xe = ((pw + 1) * sw + 6) / 7 + dx;
    // ye <= sh <= 23 (staged rows), xe-1+dx <= 23+1 < 32 (staged cols): in-region.

    const float* src0 = x + c0 * (HF * WF) + ry * WF + x02;
    float* outp = out + (size_t)(n * CCH + c0) * 49 + lane;

    for (int it = 0; it < 16; ++it) {
        const float* src = src0 + it * (HF * WF);
        #pragma unroll
        for (int j = 0; j < 6; ++j) {
            if (j < jmax) {
                const int y = (j << 2) + ly;                 // <= 23
                // global offset max: 511*2500 + 47*50 + 24 + 30 + 1 < 1.28e6: in bounds
                const float2 v = *(const float2*)(src + y * WF + lx);
                *(float2*)&R[y * RSTR + lx] = v;
            }
        }
        __syncthreads();
        if (lane < 49) {
            float m = -INFINITY;
            for (int y = ys; y < ye; ++y) {
                const float* row = &R[y * RSTR];
                for (int xx = xs; xx < xe; ++xx)
                    m = fmaxf(m, row[xx]);
            }
            outp[it * 49] = m;
        }
        __syncthreads();
    }
}

extern "C" void kernel_launch(void* const* d_in, const int* in_sizes, int n_in,
                              void* d_out, int out_size, void* d_ws, size_t ws_size,
                              hipStream_t stream) {
    const float* x    = (const float*)d_in[0];   // (1, 512, 50, 50)
    // d_in[1] is img — only its shape matters (scale 0.0625 hardcoded)
    const float* rois = (const float*)d_in[2];   // (256, 4)
    float* out = (float*)d_out;                  // (256, 512, 7, 7) fp32

    // 2048 blocks * 4 waves = 8192 waves = 256 RoIs * 32 waves; 16 channels/wave.
    roipool_kernel<<<2048, 256, 0, stream>>>(x, rois, out);
}

// Round 3
// 44.269 us; speedup vs baseline: 1.4090x; 1.4090x over previous
//
#include <hip/hip_runtime.h>

#define OUTP 7
#define CCH  512
#define HF   50
#define WF   50
#define NROI 256
#define WS_NEEDED (HF * WF * CCH * sizeof(float))   // 5.12 MB transposed map

// ---------- Kernel 1: transpose [C][H][W] -> [H][W][C] into ws ----------
// Block = (y, cg): 64 channels x one row (50 cols). 400 blocks x 256 threads.
__global__ __launch_bounds__(256) void transpose_kernel(
    const float* __restrict__ x, float* __restrict__ xt)
{
    __shared__ float tile[64][51];                 // 51: odd stride, conflict-free
    const int y  = blockIdx.x >> 3;
    const int c0 = (blockIdx.x & 7) << 6;
    const int t  = threadIdx.x;
    const int wv = t >> 6, lane = t & 63;

    // read: each wave loads 16 channel-rows, lanes across x (coalesced, ~4 lines)
    for (int r = 0; r < 16; ++r) {
        const int cl = wv * 16 + r;
        if (lane < WF)
            tile[cl][lane] = x[(c0 + cl) * (HF * WF) + y * WF + lane];
    }
    __syncthreads();

    // write: lanes across channels (contiguous 256B)
    const int xpart = t >> 6, clocal = t & 63;
    for (int k = 0; k < 13; ++k) {
        const int xx = xpart + 4 * k;
        if (xx < WF)
            xt[(y * WF + xx) * CCH + c0 + clocal] = tile[clocal][xx];
    }
}

// ---------- Kernel 2: pool from transposed map ----------
// Block = (n, c-group of 64). Wave-uniform windows; lanes = 64 channels.
__global__ __launch_bounds__(256) void roipool_t_kernel(
    const float* __restrict__ xt,
    const float* __restrict__ rois,
    float* __restrict__ out)
{
    __shared__ float ob[64 * 49];                  // 12.25 KB staged outputs

    const int n  = blockIdx.x >> 3;
    const int c0 = (blockIdx.x & 7) << 6;
    const int t  = threadIdx.x;
    const int wv = t >> 6, lane = t & 63;

    // scale 50/800 = 0.0625 exact; (int) trunc == jnp astype(int32)
    const float4 rv = *(const float4*)(rois + n * 4);
    const int rx = (int)(rv.x * 0.0625f);
    const int ry = (int)(rv.y * 0.0625f);
    const int sw = (int)(rv.z * 0.0625f) + 1;      // <= 23
    const int sh = (int)(rv.w * 0.0625f) + 1;      // <= 23

    for (int task = wv; task < 49; task += 4) {
        const int ph = task / 7;
        const int pw = task - ph * 7;
        const int ys = ry + (ph * sh) / 7;
        const int ye = ry + ((ph + 1) * sh + 6) / 7;   // ceil; <= ry+sh <= 47
        const int xs = rx + (pw * sw) / 7;
        const int xe = rx + ((pw + 1) * sw + 6) / 7;   // <= rx+sw <= 47

        float m = -INFINITY;
        for (int y = ys; y < ye; ++y) {
            const float* rp = xt + (y * WF + xs) * CCH + c0 + lane;
            for (int xx = xs; xx < xe; ++xx) {
                m = fmaxf(m, *rp);
                rp += CCH;
            }
        }
        ob[lane * 49 + task] = m;                  // bank (17c+task)%32: conflict-free
    }
    __syncthreads();

    // one contiguous 12.25 KB burst per block
    float* op = out + (size_t)(n * CCH + c0) * 49;
    for (int i = t; i < 64 * 49; i += 256)
        op[i] = ob[i];
}

// ---------- Fallback (R1 direct) if ws too small ----------
__global__ __launch_bounds__(256) void roipool_direct(
    const float* __restrict__ x, const float* __restrict__ rois,
    float* __restrict__ out, int total)
{
    const int stride = gridDim.x * blockDim.x;
    for (int idx = blockIdx.x * blockDim.x + threadIdx.x; idx < total; idx += stride) {
        int n = idx / (CCH * 49), rem = idx - n * (CCH * 49);
        int c = rem / 49, pp = rem - c * 49;
        int ph = pp / 7, pw = pp - ph * 7;
        const float* r = rois + n * 4;
        int rx = (int)(r[0] * 0.0625f), ry = (int)(r[1] * 0.0625f);
        int sw = (int)(r[2] * 0.0625f) + 1, sh = (int)(r[3] * 0.0625f) + 1;
        int ys = ry + (ph * sh) / 7, ye = ry + ((ph + 1) * sh + 6) / 7;
        int xs = rx + (pw * sw) / 7, xe = rx + ((pw + 1) * sw + 6) / 7;
        const float* f = x + c * (HF * WF);
        float m = -INFINITY;
        for (int y = ys; y < ye; ++y)
            for (int xx = xs; xx < xe; ++xx)
                m = fmaxf(m, f[y * WF + xx]);
        out[idx] = m;
    }
}

extern "C" void kernel_launch(void* const* d_in, const int* in_sizes, int n_in,
                              void* d_out, int out_size, void* d_ws, size_t ws_size,
                              hipStream_t stream) {
    const float* x    = (const float*)d_in[0];   // (1, 512, 50, 50)
    const float* rois = (const float*)d_in[2];   // (256, 4)
    float* out = (float*)d_out;                  // (256, 512, 7, 7) fp32

    if (ws_size >= WS_NEEDED) {
        float* xt = (float*)d_ws;
        transpose_kernel<<<HF * 8, 256, 0, stream>>>(x, xt);
        roipool_t_kernel<<<NROI * 8, 256, 0, stream>>>(xt, rois, out);
    } else {
        const int total = NROI * CCH * 49;
        roipool_direct<<<2048, 256, 0, stream>>>(x, rois, out, total);
    }
}

// Round 4
// 32.487 us; speedup vs baseline: 1.9200x; 1.3627x over previous
//
#include <hip/hip_runtime.h>

#define OUTP 7
#define CCH  512
#define HF   50
#define WF   50
#define NROI 256
#define WS_NEEDED (HF * WF * CCH * sizeof(float))   // 5.12 MB transposed map
#define ROWSTR (WF * 128)                           // 6400 floats between y rows (within a cg)

// ---------- Kernel 1: transpose [C][H][W] -> [cg128][H][W][128] into ws ----------
// Block = (y, 64-channel group): 400 blocks x 256 threads.
__global__ __launch_bounds__(256) void transpose_kernel(
    const float* __restrict__ x, float* __restrict__ xt)
{
    __shared__ float tile[64][51];                 // odd stride: conflict-free
    const int y  = blockIdx.x >> 3;
    const int c0 = (blockIdx.x & 7) << 6;          // 0,64,...,448 (within one 128-group)
    const int t  = threadIdx.x;
    const int wv = t >> 6, lane = t & 63;

    // read: lanes across x (coalesced)
    for (int r = 0; r < 16; ++r) {
        const int cl = wv * 16 + r;
        if (lane < WF)
            tile[cl][lane] = x[(c0 + cl) * (HF * WF) + y * WF + lane];
    }
    __syncthreads();

    // write: lanes across channels (contiguous 256B), blocked layout
    const int g   = c0 >> 7;                       // 128-group id
    const int cin = (c0 & 127);                    // 0 or 64
    for (int k = 0; k < 13; ++k) {
        const int xx = (t >> 6) + 4 * k;
        if (xx < WF)
            xt[((size_t)g * (HF * WF) + y * WF + xx) * 128 + cin + (t & 63)]
                = tile[t & 63][xx];
    }
}

// ---------- Kernel 2: pool from blocked-transposed map ----------
// Block = (n, cg of 128 channels): 1024 blocks. Lanes = channels via float2.
__global__ __launch_bounds__(256) void roipool_t_kernel(
    const float* __restrict__ xt,
    const float* __restrict__ rois,
    float* __restrict__ out)
{
    __shared__ float ob[49 * 130];                 // [task][130]: 2-way banks (free)

    const int n  = blockIdx.x >> 2;
    const int cg = blockIdx.x & 3;
    const int t  = threadIdx.x;
    const int wv = t >> 6, lane = t & 63;

    // scale 50/800 = 0.0625 exact; (int) trunc == jnp astype(int32)
    const float4 rv = *(const float4*)(rois + n * 4);
    const int rx = (int)(rv.x * 0.0625f);
    const int ry = (int)(rv.y * 0.0625f);
    const int sw = (int)(rv.z * 0.0625f) + 1;      // 6..23
    const int sh = (int)(rv.w * 0.0625f) + 1;      // 6..23

    const float* part = xt + (size_t)cg * (HF * WF * 128) + 2 * lane;

#define M2(a) { m.x = fmaxf(m.x, (a).x); m.y = fmaxf(m.y, (a).y); }
#define LD(k) (*(const float2*)(rp + (k) * 128))

    for (int task = wv; task < 49; task += 4) {
        const int ph = task / 7;
        const int pw = task - ph * 7;
        const int ys = ry + (ph * sh) / 7;
        const int ye = ry + ((ph + 1) * sh + 6) / 7;   // <= 47
        const int xs = rx + (pw * sw) / 7;
        const int xe = rx + ((pw + 1) * sw + 6) / 7;   // <= 47
        const int yspan = ye - ys;                     // 1..5
        const float* rp = part + (ys * WF + xs) * 128;

        float2 m = make_float2(-INFINITY, -INFINITY);
        switch (xe - xs) {                             // 1..5, wave-uniform
        case 1:
            for (int y = 0; y < yspan; ++y) { float2 a0 = LD(0); M2(a0); rp += ROWSTR; }
            break;
        case 2:
            for (int y = 0; y < yspan; ++y) { float2 a0 = LD(0), a1 = LD(1);
                M2(a0); M2(a1); rp += ROWSTR; }
            break;
        case 3:
            for (int y = 0; y < yspan; ++y) { float2 a0 = LD(0), a1 = LD(1), a2 = LD(2);
                M2(a0); M2(a1); M2(a2); rp += ROWSTR; }
            break;
        case 4:
            for (int y = 0; y < yspan; ++y) { float2 a0 = LD(0), a1 = LD(1), a2 = LD(2), a3 = LD(3);
                M2(a0); M2(a1); M2(a2); M2(a3); rp += ROWSTR; }
            break;
        default:
            for (int y = 0; y < yspan; ++y) { float2 a0 = LD(0), a1 = LD(1), a2 = LD(2), a3 = LD(3), a4 = LD(4);
                M2(a0); M2(a1); M2(a2); M2(a3); M2(a4); rp += ROWSTR; }
            break;
        }
        *(float2*)&ob[task * 130 + 2 * lane] = m;
    }
#undef LD
#undef M2
    __syncthreads();

    // contiguous coalesced burst: 128 ch x 49 tasks = 6272 floats
    float* op = out + (size_t)(n * CCH + cg * 128) * 49;
    int c = t / 49, task = t - c * 49;
    for (int i = t; i < 128 * 49; i += 256) {
        op[i] = ob[task * 130 + c];
        task += 11; c += 5;                        // 256 = 5*49 + 11
        if (task >= 49) { task -= 49; c += 1; }
    }
}

// ---------- Fallback (direct) if ws too small ----------
__global__ __launch_bounds__(256) void roipool_direct(
    const float* __restrict__ x, const float* __restrict__ rois,
    float* __restrict__ out, int total)
{
    const int stride = gridDim.x * blockDim.x;
    for (int idx = blockIdx.x * blockDim.x + threadIdx.x; idx < total; idx += stride) {
        int n = idx / (CCH * 49), rem = idx - n * (CCH * 49);
        int c = rem / 49, pp = rem - c * 49;
        int ph = pp / 7, pw = pp - ph * 7;
        const float* r = rois + n * 4;
        int rx = (int)(r[0] * 0.0625f), ry = (int)(r[1] * 0.0625f);
        int sw = (int)(r[2] * 0.0625f) + 1, sh = (int)(r[3] * 0.0625f) + 1;
        int ys = ry + (ph * sh) / 7, ye = ry + ((ph + 1) * sh + 6) / 7;
        int xs = rx + (pw * sw) / 7, xe = rx + ((pw + 1) * sw + 6) / 7;
        const float* f = x + c * (HF * WF);
        float m = -INFINITY;
        for (int y = ys; y < ye; ++y)
            for (int xx = xs; xx < xe; ++xx)
                m = fmaxf(m, f[y * WF + xx]);
        out[idx] = m;
    }
}

extern "C" void kernel_launch(void* const* d_in, const int* in_sizes, int n_in,
                              void* d_out, int out_size, void* d_ws, size_t ws_size,
                              hipStream_t stream) {
    const float* x    = (const float*)d_in[0];   // (1, 512, 50, 50)
    const float* rois = (const float*)d_in[2];   // (256, 4)
    float* out = (float*)d_out;                  // (256, 512, 7, 7) fp32

    if (ws_size >= WS_NEEDED) {
        float* xt = (float*)d_ws;
        transpose_kernel<<<HF * 8, 256, 0, stream>>>(x, xt);
        roipool_t_kernel<<<NROI * 4, 256, 0, stream>>>(xt, rois, out);
    } else {
        const int total = NROI * CCH * 49;
        roipool_direct<<<2048, 256, 0, stream>>>(x, rois, out, total);
    }
}

// Round 5
// 25.802 us; speedup vs baseline: 2.4174x; 1.2591x over previous
//
#include <hip/hip_runtime.h>

#define OUTP 7
#define CCH  512
#define HF   50
#define WF   50
#define NROI 256
#define WS_NEEDED (HF * WF * CCH * sizeof(float))   // 5.12 MB transposed map
#define ROWSTR (WF * 256)                           // floats between y rows (within cg256)
#define OBSTR 258                                   // LDS stage stride (floats)

// ---------- Kernel 1: transpose [C][H][W] -> [cg256][H][W][256] into ws ----------
__global__ __launch_bounds__(256) void transpose_kernel(
    const float* __restrict__ x, float* __restrict__ xt)
{
    __shared__ float tile[64][51];                 // odd stride: conflict-free
    const int y  = blockIdx.x >> 3;
    const int c0 = (blockIdx.x & 7) << 6;
    const int t  = threadIdx.x;
    const int wv = t >> 6, lane = t & 63;

    for (int r = 0; r < 16; ++r) {
        const int cl = wv * 16 + r;
        if (lane < WF)
            tile[cl][lane] = x[(c0 + cl) * (HF * WF) + y * WF + lane];
    }
    __syncthreads();

    const int g   = c0 >> 8;                       // 256-group id (0/1)
    const int cin = c0 & 255;
    for (int k = 0; k < 13; ++k) {
        const int xx = (t >> 6) + 4 * k;
        if (xx < WF)
            xt[((size_t)g * (HF * WF) + y * WF + xx) * 256 + cin + (t & 63)]
                = tile[t & 63][xx];
    }
}

// ---------- Kernel 2: pool from blocked-transposed map ----------
// Block = (n, cg of 256 channels): 512 blocks x 512 threads (8 waves).
// Lanes = 256 channels via float4; windows wave-uniform (zero divergence).
__global__ __launch_bounds__(512) void roipool_t_kernel(
    const float* __restrict__ xt,
    const float* __restrict__ rois,
    float* __restrict__ out)
{
    __shared__ float ob[49 * OBSTR];               // 50.6 KB staged outputs

    const int n  = blockIdx.x >> 1;
    const int cg = blockIdx.x & 1;                 // == xcd&1: one 2.56MB L2 partition/XCD
    const int t  = threadIdx.x;
    const int wv = t >> 6, lane = t & 63;

    // scale 50/800 = 0.0625 exact; (int) trunc == jnp astype(int32)
    const float4 rv = *(const float4*)(rois + n * 4);
    const int rx = (int)(rv.x * 0.0625f);
    const int ry = (int)(rv.y * 0.0625f);
    const int sw = (int)(rv.z * 0.0625f) + 1;      // 6..23
    const int sh = (int)(rv.w * 0.0625f) + 1;      // 6..23

    const float* part = xt + (size_t)cg * (HF * WF * 256) + 4 * lane;

#define M4(a) { m.x = fmaxf(m.x,(a).x); m.y = fmaxf(m.y,(a).y); \
                m.z = fmaxf(m.z,(a).z); m.w = fmaxf(m.w,(a).w); }
#define LD(k) (*(const float4*)(rp + (k) * 256))

    for (int task = wv; task < 49; task += 8) {
        const int ph = task / 7;
        const int pw = task - ph * 7;
        const int ys = ry + (ph * sh) / 7;
        const int ye = ry + ((ph + 1) * sh + 6) / 7;   // <= 47
        const int xs = rx + (pw * sw) / 7;
        const int xe = rx + ((pw + 1) * sw + 6) / 7;   // <= 47
        const int yspan = ye - ys;                     // 1..5
        const float* rp = part + (ys * WF + xs) * 256;

        float4 m = make_float4(-INFINITY, -INFINITY, -INFINITY, -INFINITY);
        switch (xe - xs) {                             // 1..5, wave-uniform
        case 1:
            for (int y = 0; y < yspan; ++y) { float4 a0 = LD(0); M4(a0); rp += ROWSTR; }
            break;
        case 2:
            for (int y = 0; y < yspan; ++y) { float4 a0 = LD(0), a1 = LD(1);
                M4(a0); M4(a1); rp += ROWSTR; }
            break;
        case 3:
            for (int y = 0; y < yspan; ++y) { float4 a0 = LD(0), a1 = LD(1), a2 = LD(2);
                M4(a0); M4(a1); M4(a2); rp += ROWSTR; }
            break;
        case 4:
            for (int y = 0; y < yspan; ++y) { float4 a0 = LD(0), a1 = LD(1), a2 = LD(2), a3 = LD(3);
                M4(a0); M4(a1); M4(a2); M4(a3); rp += ROWSTR; }
            break;
        default:
            for (int y = 0; y < yspan; ++y) { float4 a0 = LD(0), a1 = LD(1), a2 = LD(2), a3 = LD(3), a4 = LD(4);
                M4(a0); M4(a1); M4(a2); M4(a3); M4(a4); rp += ROWSTR; }
            break;
        }
        // conflict-free contiguous float2 writes
        *(float2*)&ob[task * OBSTR + 4 * lane]     = make_float2(m.x, m.y);
        *(float2*)&ob[task * OBSTR + 4 * lane + 2] = make_float2(m.z, m.w);
    }
#undef LD
#undef M4
    __syncthreads();

    // coalesced burst: 256 ch x 49 tasks; nontemporal -> don't evict xt from L2
    float* op = out + (size_t)(n * CCH + cg * 256) * 49;
    int c = t / 49, task = t - c * 49;
    for (int i = t; i < 256 * 49; i += 512) {
        __builtin_nontemporal_store(ob[task * OBSTR + c], &op[i]);
        task += 22; c += 10;                       // 512 = 10*49 + 22
        if (task >= 49) { task -= 49; c += 1; }
    }
}

// ---------- Fallback (direct) if ws too small ----------
__global__ __launch_bounds__(256) void roipool_direct(
    const float* __restrict__ x, const float* __restrict__ rois,
    float* __restrict__ out, int total)
{
    const int stride = gridDim.x * blockDim.x;
    for (int idx = blockIdx.x * blockDim.x + threadIdx.x; idx < total; idx += stride) {
        int n = idx / (CCH * 49), rem = idx - n * (CCH * 49);
        int c = rem / 49, pp = rem - c * 49;
        int ph = pp / 7, pw = pp - ph * 7;
        const float* r = rois + n * 4;
        int rx = (int)(r[0] * 0.0625f), ry = (int)(r[1] * 0.0625f);
        int sw = (int)(r[2] * 0.0625f) + 1, sh = (int)(r[3] * 0.0625f) + 1;
        int ys = ry + (ph * sh) / 7, ye = ry + ((ph + 1) * sh + 6) / 7;
        int xs = rx + (pw * sw) / 7, xe = rx + ((pw + 1) * sw + 6) / 7;
        const float* f = x + c * (HF * WF);
        float m = -INFINITY;
        for (int y = ys; y < ye; ++y)
            for (int xx = xs; xx < xe; ++xx)
                m = fmaxf(m, f[y * WF + xx]);
        out[idx] = m;
    }
}

extern "C" void kernel_launch(void* const* d_in, const int* in_sizes, int n_in,
                              void* d_out, int out_size, void* d_ws, size_t ws_size,
                              hipStream_t stream) {
    const float* x    = (const float*)d_in[0];   // (1, 512, 50, 50)
    const float* rois = (const float*)d_in[2];   // (256, 4)
    float* out = (float*)d_out;                  // (256, 512, 7, 7) fp32

    if (ws_size >= WS_NEEDED) {
        float* xt = (float*)d_ws;
        transpose_kernel<<<HF * 8, 256, 0, stream>>>(x, xt);
        roipool_t_kernel<<<NROI * 2, 512, 0, stream>>>(xt, rois, out);
    } else {
        const int total = NROI * CCH * 49;
        roipool_direct<<<2048, 256, 0, stream>>>(x, rois, out, total);
    }
}